// Round 12
// baseline (189.456 us; speedup 1.0000x reference)
//
#include <hip/hip_runtime.h>
#include <math.h>

#define L_SEQ 2048
#define DMODEL 1024
#define HEADS 16
#define HD 64
#define BATCH 2
#define MROWS (BATCH*L_SEQ)   // 4096
#define KDIM 1024
#define VSTRIDE 2136          // v^T row stride (shorts): 64 front pad + 2048 + 24 tail

typedef short bfrag8 __attribute__((ext_vector_type(8)));   // 8 bf16 = 4 VGPRs
typedef float f32x4f __attribute__((ext_vector_type(4)));

__device__ __forceinline__ unsigned short f2bf(float f) {
    unsigned u = __float_as_uint(f);
    unsigned r = u + 0x7FFFu + ((u >> 16) & 1u);   // RNE
    return (unsigned short)(r >> 16);
}
__device__ __forceinline__ float bf2f(unsigned short h) {
    return __uint_as_float(((unsigned)h) << 16);
}

// ---------------- fp32 -> bf16 convert (x + 4 weights) + zero kmean_acc ------
// blocks 0..4095: x; 4096..8191: weights; 8192: zero kmean accumulator.
__global__ __launch_bounds__(256) void convert_bf16(
    const float* __restrict__ x, const float* __restrict__ wq,
    const float* __restrict__ wk, const float* __restrict__ wv,
    const float* __restrict__ wo,
    unsigned short* __restrict__ xb, unsigned short* __restrict__ qwb,
    unsigned short* __restrict__ kwb, unsigned short* __restrict__ vwb,
    unsigned short* __restrict__ owb, float* __restrict__ kmean_acc)
{
    const int bid = blockIdx.x;
    if (bid == 8192) {
        float4 z = make_float4(0.f, 0.f, 0.f, 0.f);
        *(float4*)&kmean_acc[threadIdx.x * 8]     = z;
        *(float4*)&kmean_acc[threadIdx.x * 8 + 4] = z;
        return;
    }
    const float* src; unsigned short* dst; size_t base;
    if (bid < 4096) { src = x; dst = xb; base = (size_t)bid * 1024; }
    else {
        const int r = bid - 4096; const int w = r >> 10; const int off = r & 1023;
        src = (w==0) ? wq : (w==1) ? wk : (w==2) ? wv : wo;
        dst = (w==0) ? qwb : (w==1) ? kwb : (w==2) ? vwb : owb;
        base = (size_t)off * 1024;
    }
    const size_t idx = base + (size_t)threadIdx.x * 4;
    float4 v = *(const float4*)&src[idx];
    ushort4 o;
    o.x = f2bf(v.x); o.y = f2bf(v.y); o.z = f2bf(v.z); o.w = f2bf(v.w);
    *(ushort4*)&dst[idx] = o;
}

// ---------------- MFMA bf16 QKV GEMM: 64x128 tiles (M-split, 6 blocks/CU) ---
// BK=64, both operands via global_load_lds, XOR-swizzled LDS (k-group cg of
// row r holds global cg ^ (r&7); ds_read unswizzles -> conflict-free b128).
// M-split 128->64 mirrors the out-proj win: smaller per-block drain, ~2x more
// resident blocks/CU -> drain phases interleave with other blocks' MFMA.
// N=3072 logical over {Wq,Wk,Wv}; q,k -> bf16 head-split [b,h,l,d];
// v -> TRANSPOSED padded [b,h,d,64+l]; k-blocks accumulate kmean_acc.
#define GBK 64

__global__ void mfma_gemm_qkv(
    const unsigned short* __restrict__ A,
    const unsigned short* __restrict__ W0, const unsigned short* __restrict__ W1,
    const unsigned short* __restrict__ W2,
    unsigned short* __restrict__ qo, unsigned short* __restrict__ ko,
    unsigned short* __restrict__ vo, float* __restrict__ kmean_acc)
{
    __shared__ short As[64*GBK];    // 8 KB
    __shared__ short Bs[128*GBK];   // 16 KB

    const int tid  = threadIdx.x;
    const int wave = tid >> 6, lane = tid & 63;
    const int m0   = blockIdx.x * 64;
    const int n0g  = blockIdx.y * 128;

    const int which = n0g >> 10;                // uniform per block
    const int n0 = n0g & 1023;
    const unsigned short* Wp = (which==0) ? W0 : (which==1) ? W1 : W2;

    const int quad = lane >> 4, lm = lane & 15;
    const int wm = wave >> 1, wn = wave & 1;   // wave tile: 32 rows x 64 cols

    f32x4f acc[2][4] = {};

    // A staging: wave stages rows [wave*16, +16), 2 issues x 512 elems
    const int sea   = wave * 1024 + lane * 8;
    const int srowa = sea >> 6;
    const int sga   = ((((sea & 63) >> 3) ^ (srowa & 7)) << 3);
    // B staging: wave stages rows [wave*32, +32), 4 issues x 512 elems
    const int seb   = wave * 2048 + lane * 8;
    const int srowb = seb >> 6;
    const int sgb   = ((((seb & 63) >> 3) ^ (srowb & 7)) << 3);

    for (int k0 = 0; k0 < KDIM; k0 += GBK) {
        __syncthreads();
        #pragma unroll
        for (int i = 0; i < 2; ++i) {
            const int ebase = wave * 1024 + i * 512;
            const int row = srowa + i * 8;
            __builtin_amdgcn_global_load_lds(
                (const __attribute__((address_space(1))) void*)(A + (size_t)(m0 + row) * KDIM + k0 + sga),
                (__attribute__((address_space(3))) void*)(&As[ebase]), 16, 0, 0);
        }
        #pragma unroll
        for (int i = 0; i < 4; ++i) {
            const int ebase = wave * 2048 + i * 512;
            const int row = srowb + i * 8;
            __builtin_amdgcn_global_load_lds(
                (const __attribute__((address_space(1))) void*)(Wp + (size_t)(n0 + row) * KDIM + k0 + sgb),
                (__attribute__((address_space(3))) void*)(&Bs[ebase]), 16, 0, 0);
        }
        __syncthreads();

        #pragma unroll
        for (int kk = 0; kk < 2; ++kk) {
            bfrag8 af[2], bf[4];
            #pragma unroll
            for (int t = 0; t < 2; ++t) {
                const int ar = wm*32 + t*16 + lm;
                af[t] = *(const bfrag8*)&As[ar*GBK + (((kk*4 + quad) ^ (ar & 7)) << 3)];
            }
            #pragma unroll
            for (int t = 0; t < 4; ++t) {
                const int br = wn*64 + t*16 + lm;
                bf[t] = *(const bfrag8*)&Bs[br*GBK + (((kk*4 + quad) ^ (br & 7)) << 3)];
            }
            #pragma unroll
            for (int mt = 0; mt < 2; ++mt)
                #pragma unroll
                for (int nt = 0; nt < 4; ++nt)
                    acc[mt][nt] = __builtin_amdgcn_mfma_f32_16x16x32_bf16(
                        af[mt], bf[nt], acc[mt][nt], 0, 0, 0);
        }
    }

    // epilogue: C/D layout col=lane&15, row=quad*4+reg
    if (which == 2) {
        // v: transposed padded layout, coalesced ushort4 (4 consecutive l)
        #pragma unroll
        for (int mt = 0; mt < 2; ++mt)
            #pragma unroll
            for (int nt = 0; nt < 4; ++nt) {
                const int gn = n0 + wn*64 + nt*16 + lm;
                const int h = gn >> 6, d = gn & 63;
                const int gm0 = m0 + wm*32 + mt*16 + quad*4;
                const int b = gm0 >> 11, l0 = gm0 & (L_SEQ-1);
                ushort4 o;
                o.x = f2bf(acc[mt][nt][0]); o.y = f2bf(acc[mt][nt][1]);
                o.z = f2bf(acc[mt][nt][2]); o.w = f2bf(acc[mt][nt][3]);
                *(ushort4*)&vo[((size_t)((b*HEADS + h)*HD + d))*VSTRIDE + 64 + l0] = o;
            }
    } else {
        unsigned short* Cp = (which==0) ? qo : ko;
        #pragma unroll
        for (int mt = 0; mt < 2; ++mt)
            #pragma unroll
            for (int nt = 0; nt < 4; ++nt) {
                const int gn = n0 + wn*64 + nt*16 + lm;
                const int h = gn >> 6, d = gn & 63;
                #pragma unroll
                for (int r = 0; r < 4; ++r) {
                    const int gm = m0 + wm*32 + mt*16 + quad*4 + r;
                    const int b = gm >> 11, l = gm & (L_SEQ-1);
                    Cp[(((size_t)(b*HEADS + h) * L_SEQ) + l) * HD + d] = f2bf(acc[mt][nt][r]);
                }
            }
        if (which == 1) {
            const int b = m0 >> 11;
            #pragma unroll
            for (int nt = 0; nt < 4; ++nt) {
                const int gn = n0 + wn*64 + nt*16 + lm;
                const int h = gn >> 6, d = gn & 63;
                float s = 0.f;
                #pragma unroll
                for (int mt = 0; mt < 2; ++mt)
                    #pragma unroll
                    for (int r = 0; r < 4; ++r) s += acc[mt][nt][r];
                atomicAdd(&kmean_acc[(size_t)(b*HEADS + h)*HD + d], s);
            }
        }
    }
}

// ---------------- out-projection GEMM: 64x128 tiles (M-split for occupancy) --
// grid (64,8) = 512 blocks = 2/CU: barrier drains of resident blocks
// interleave. Plain coalesced fp32 writes (split-K atomics were write-bound).
__global__ void out_proj_gemm(
    const unsigned short* __restrict__ A, const unsigned short* __restrict__ W,
    float* __restrict__ C)
{
    __shared__ short As[64*GBK];    // 8 KB
    __shared__ short Bs[128*GBK];   // 16 KB

    const int tid  = threadIdx.x;
    const int wave = tid >> 6, lane = tid & 63;
    const int m0   = blockIdx.x * 64;
    const int n0   = blockIdx.y * 128;

    const int quad = lane >> 4, lm = lane & 15;
    const int wm = wave >> 1, wn = wave & 1;   // wave tile: 32 rows x 64 cols

    f32x4f acc[2][4] = {};

    const int sea   = wave * 1024 + lane * 8;
    const int srowa = sea >> 6;
    const int sga   = ((((sea & 63) >> 3) ^ (srowa & 7)) << 3);
    const int seb   = wave * 2048 + lane * 8;
    const int srowb = seb >> 6;
    const int sgb   = ((((seb & 63) >> 3) ^ (srowb & 7)) << 3);

    for (int k0 = 0; k0 < KDIM; k0 += GBK) {
        __syncthreads();
        #pragma unroll
        for (int i = 0; i < 2; ++i) {
            const int ebase = wave * 1024 + i * 512;
            const int row = srowa + i * 8;
            __builtin_amdgcn_global_load_lds(
                (const __attribute__((address_space(1))) void*)(A + (size_t)(m0 + row) * KDIM + k0 + sga),
                (__attribute__((address_space(3))) void*)(&As[ebase]), 16, 0, 0);
        }
        #pragma unroll
        for (int i = 0; i < 4; ++i) {
            const int ebase = wave * 2048 + i * 512;
            const int row = srowb + i * 8;
            __builtin_amdgcn_global_load_lds(
                (const __attribute__((address_space(1))) void*)(W + (size_t)(n0 + row) * KDIM + k0 + sgb),
                (__attribute__((address_space(3))) void*)(&Bs[ebase]), 16, 0, 0);
        }
        __syncthreads();

        #pragma unroll
        for (int kk = 0; kk < 2; ++kk) {
            bfrag8 af[2], bf[4];
            #pragma unroll
            for (int t = 0; t < 2; ++t) {
                const int ar = wm*32 + t*16 + lm;
                af[t] = *(const bfrag8*)&As[ar*GBK + (((kk*4 + quad) ^ (ar & 7)) << 3)];
            }
            #pragma unroll
            for (int t = 0; t < 4; ++t) {
                const int br = wn*64 + t*16 + lm;
                bf[t] = *(const bfrag8*)&Bs[br*GBK + (((kk*4 + quad) ^ (br & 7)) << 3)];
            }
            #pragma unroll
            for (int mt = 0; mt < 2; ++mt)
                #pragma unroll
                for (int nt = 0; nt < 4; ++nt)
                    acc[mt][nt] = __builtin_amdgcn_mfma_f32_16x16x32_bf16(
                        af[mt], bf[nt], acc[mt][nt], 0, 0, 0);
        }
    }

    #pragma unroll
    for (int mt = 0; mt < 2; ++mt)
        #pragma unroll
        for (int nt = 0; nt < 4; ++nt) {
            const int gn = n0 + wn*64 + nt*16 + lm;
            #pragma unroll
            for (int r = 0; r < 4; ++r) {
                const int gm = m0 + wm*32 + mt*16 + quad*4 + r;
                C[(size_t)gm * DMODEL + gn] = acc[mt][nt][r];
            }
        }
}

// ---------------- MFMA windowed attention, zero-staging ----------------
// Block = one (b,h) x 64 queries; 4 waves x 16 queries. Window base j0 = q0-64,
// 6 QK key-tiles (96 rel slots, all computed; invalid -> masked -> P=0).
// K B-frags and V^T B-frags read DIRECTLY from global (16B aligned by design).
// Only LDS: the P round-trip buffer (per-wave rows -> no barriers at all).
#define P_STRIDE 104    // shorts

__global__ __launch_bounds__(256) void attn_kernel(
    const unsigned short* __restrict__ qb, const unsigned short* __restrict__ kb,
    const unsigned short* __restrict__ vt, const float* __restrict__ kmean_acc,
    const float* __restrict__ g_sep, const float* __restrict__ g_align,
    const float* __restrict__ g_coh, unsigned short* __restrict__ out)
{
    __shared__ unsigned short pl[64 * P_STRIDE];

    const int tid = threadIdx.x;
    const int bh = blockIdx.x >> 5;        // 32 q-tiles per (b,h)
    const int qt = blockIdx.x & 31;
    const int q0 = qt * 64;
    const int j0 = q0 - 64;

    const int w = tid >> 6, lane = tid & 63;
    const int quad = lane >> 4, lm = lane & 15;
    const float sep = g_sep[0], align = g_align[0], coh = g_coh[0];

    const unsigned short* kbh = kb + (size_t)bh * L_SEQ * HD;
    const unsigned short* vbh = vt + (size_t)bh * HD * VSTRIDE;

    // Q a-frags (A[m=lm][k=quad*8+j], ksteps 0/1)
    const unsigned short* qrow =
        qb + ((size_t)bh * L_SEQ + q0 + w*16 + lm) * HD + quad * 8;
    bfrag8 qa0 = *(const bfrag8*)qrow;
    bfrag8 qa1 = *(const bfrag8*)(qrow + 32);

    // q . kmean for the cohesion mean (kmean_acc is a SUM over l; scale here)
    const float* kmp = kmean_acc + bh * HD + quad * 8;
    float4 km0 = *(const float4*)(kmp);
    float4 km1 = *(const float4*)(kmp + 4);
    float4 km2 = *(const float4*)(kmp + 32);
    float4 km3 = *(const float4*)(kmp + 36);
    float part =
        bf2f((unsigned short)qa0[0])*km0.x + bf2f((unsigned short)qa0[1])*km0.y +
        bf2f((unsigned short)qa0[2])*km0.z + bf2f((unsigned short)qa0[3])*km0.w +
        bf2f((unsigned short)qa0[4])*km1.x + bf2f((unsigned short)qa0[5])*km1.y +
        bf2f((unsigned short)qa0[6])*km1.z + bf2f((unsigned short)qa0[7])*km1.w +
        bf2f((unsigned short)qa1[0])*km2.x + bf2f((unsigned short)qa1[1])*km2.y +
        bf2f((unsigned short)qa1[2])*km2.z + bf2f((unsigned short)qa1[3])*km2.w +
        bf2f((unsigned short)qa1[4])*km3.x + bf2f((unsigned short)qa1[5])*km3.y +
        bf2f((unsigned short)qa1[6])*km3.z + bf2f((unsigned short)qa1[7])*km3.w;
    part *= (1.f / (float)L_SEQ);
    part += __shfl_xor(part, 16, 64);
    part += __shfl_xor(part, 32, 64);
    // lane g (0..15) holds q.kmean for query w*16+g (replicated across quads)

    // QK^T: 6 tiles x 2 MFMAs, K rows direct from global (clamped; masked later)
    f32x4f sacc[6];
    #pragma unroll
    for (int t = 0; t < 6; ++t) {
        int kr = j0 + w*16 + t*16 + lm;
        kr = kr < 0 ? 0 : (kr >= L_SEQ ? L_SEQ - 1 : kr);
        const unsigned short* kp = kbh + (size_t)kr * HD + quad * 8;
        bfrag8 b0 = *(const bfrag8*)kp;
        bfrag8 b1 = *(const bfrag8*)(kp + 32);
        f32x4f z = {0.f, 0.f, 0.f, 0.f};
        z = __builtin_amdgcn_mfma_f32_16x16x32_bf16(qa0, b0, z, 0, 0, 0);
        sacc[t] = __builtin_amdgcn_mfma_f32_16x16x32_bf16(qa1, b1, z, 0, 0, 0);
    }

    // Reynolds rules + softmax per row (row = quad*4+r), P -> LDS (per-wave rows)
    float rinv[4];
    #pragma unroll
    for (int r = 0; r < 4; ++r) {
        const int row = quad*4 + r;
        const int i   = q0 + w*16 + row;
        const float mean_i = __shfl(part, row, 64) * 0.125f;
        float sc[6]; float mx = -3.0e38f;
        #pragma unroll
        for (int t = 0; t < 6; ++t) {
            const int jabs = j0 + w*16 + t*16 + lm;
            const int dist = i - jabs;
            float s = sacc[t][r] * 0.125f;
            const float sig = 1.f / (1.f + __expf(-s));
            float adj = s * (1.f + align) - sep * sig * sig - coh * fabsf(s - mean_i);
            const bool ok = (dist >= 0) && (dist < 64) && (jabs >= 0);
            sc[t] = ok ? adj : -3.0e38f;
            mx = fmaxf(mx, sc[t]);
        }
        mx = fmaxf(mx, __shfl_xor(mx, 1, 64));
        mx = fmaxf(mx, __shfl_xor(mx, 2, 64));
        mx = fmaxf(mx, __shfl_xor(mx, 4, 64));
        mx = fmaxf(mx, __shfl_xor(mx, 8, 64));
        float ls = 0.f;
        #pragma unroll
        for (int t = 0; t < 6; ++t) {
            const float p = __expf(sc[t] - mx);   // masked -> 0
            ls += p;
            pl[(w*16 + row) * P_STRIDE + t*16 + lm] = f2bf(p);
        }
        ls += __shfl_xor(ls, 1, 64);
        ls += __shfl_xor(ls, 2, 64);
        ls += __shfl_xor(ls, 4, 64);
        ls += __shfl_xor(ls, 8, 64);
        rinv[r] = 1.f / ls;
    }

    // PV: 3 ksteps x 4 d-tiles; V^T B-frags direct from global (padded rows).
    f32x4f oacc[4] = {};
    #pragma unroll
    for (int kk = 0; kk < 3; ++kk) {
        bfrag8 pa = *(const bfrag8*)&pl[(w*16 + lm) * P_STRIDE + kk*32 + quad*8];
        const int loff = 64 + j0 + w*16 + kk*32 + quad*8;
        #pragma unroll
        for (int nt = 0; nt < 4; ++nt) {
            bfrag8 bv = *(const bfrag8*)&vbh[(size_t)(nt*16 + lm) * VSTRIDE + loff];
            oacc[nt] = __builtin_amdgcn_mfma_f32_16x16x32_bf16(pa, bv, oacc[nt], 0, 0, 0);
        }
    }

    const int b = bh >> 4, h = bh & (HEADS - 1);
    #pragma unroll
    for (int nt = 0; nt < 4; ++nt)
        #pragma unroll
        for (int r = 0; r < 4; ++r) {
            const int i = q0 + w*16 + quad*4 + r;
            const int d = nt*16 + lm;
            out[((size_t)(b * L_SEQ + i)) * DMODEL + h * HD + d] =
                f2bf(oacc[nt][r] * rinv[r]);
        }
}

extern "C" void kernel_launch(void* const* d_in, const int* in_sizes, int n_in,
                              void* d_out, int out_size, void* d_ws, size_t ws_size,
                              hipStream_t stream)
{
    (void)in_sizes; (void)n_in; (void)out_size; (void)ws_size;
    const float* x     = (const float*)d_in[0];
    const float* Wq    = (const float*)d_in[1];
    const float* Wk    = (const float*)d_in[2];
    const float* Wv    = (const float*)d_in[3];
    const float* Wo    = (const float*)d_in[4];
    const float* g_sep   = (const float*)d_in[5];
    const float* g_align = (const float*)d_in[6];
    const float* g_coh   = (const float*)d_in[7];
    float* out = (float*)d_out;

    // workspace layout (~49 MB)
    float* kmean_ws = (float*)d_ws;                   // 2048 floats (sum, not mean)
    unsigned short* xb  = (unsigned short*)(kmean_ws + 2048);
    const size_t per = (size_t)MROWS * DMODEL;        // 4 Mi
    unsigned short* wqb = xb  + per;
    unsigned short* wkb = wqb + (size_t)DMODEL*KDIM;
    unsigned short* wvb = wkb + (size_t)DMODEL*KDIM;
    unsigned short* wob = wvb + (size_t)DMODEL*KDIM;
    unsigned short* qb  = wob + (size_t)DMODEL*KDIM;
    unsigned short* kb  = qb  + per;
    unsigned short* vtb = kb  + per;                  // [b,h,d,*] padded: 2048*VSTRIDE
    unsigned short* attb = vtb + (size_t)BATCH*HEADS*HD*VSTRIDE;

    convert_bf16<<<dim3(8193), dim3(256), 0, stream>>>(
        x, Wq, Wk, Wv, Wo, xb, wqb, wkb, wvb, wob, kmean_ws);
    mfma_gemm_qkv<<<dim3(MROWS/64, 3*DMODEL/128), dim3(256), 0, stream>>>(
        xb, wqb, wkb, wvb, qb, kb, vtb, kmean_ws);
    attn_kernel<<<dim3(BATCH*HEADS*(L_SEQ/64)), dim3(256), 0, stream>>>(
        qb, kb, vtb, kmean_ws, g_sep, g_align, g_coh, attb);
    out_proj_gemm<<<dim3(MROWS/64, DMODEL/128), dim3(256), 0, stream>>>(
        attb, wob, out);
}

// Round 13
// 158.326 us; speedup vs baseline: 1.1966x; 1.1966x over previous
//
#include <hip/hip_runtime.h>
#include <math.h>

#define L_SEQ 2048
#define DMODEL 1024
#define HEADS 16
#define HD 64
#define BATCH 2
#define MROWS (BATCH*L_SEQ)   // 4096
#define KDIM 1024
#define VSTRIDE 2136          // v^T row stride (shorts): 64 front pad + 2048 + 24 tail

typedef short bfrag8 __attribute__((ext_vector_type(8)));   // 8 bf16 = 4 VGPRs
typedef float f32x4f __attribute__((ext_vector_type(4)));

__device__ __forceinline__ unsigned short f2bf(float f) {
    unsigned u = __float_as_uint(f);
    unsigned r = u + 0x7FFFu + ((u >> 16) & 1u);   // RNE
    return (unsigned short)(r >> 16);
}
__device__ __forceinline__ float bf2f(unsigned short h) {
    return __uint_as_float(((unsigned)h) << 16);
}

// ---------------- fp32 -> bf16 convert (x + 4 weights) + zero kmean_acc ------
// blocks 0..4095: x; 4096..8191: weights; 8192: zero kmean accumulator.
__global__ __launch_bounds__(256) void convert_bf16(
    const float* __restrict__ x, const float* __restrict__ wq,
    const float* __restrict__ wk, const float* __restrict__ wv,
    const float* __restrict__ wo,
    unsigned short* __restrict__ xb, unsigned short* __restrict__ qwb,
    unsigned short* __restrict__ kwb, unsigned short* __restrict__ vwb,
    unsigned short* __restrict__ owb, float* __restrict__ kmean_acc)
{
    const int bid = blockIdx.x;
    if (bid == 8192) {
        float4 z = make_float4(0.f, 0.f, 0.f, 0.f);
        *(float4*)&kmean_acc[threadIdx.x * 8]     = z;
        *(float4*)&kmean_acc[threadIdx.x * 8 + 4] = z;
        return;
    }
    const float* src; unsigned short* dst; size_t base;
    if (bid < 4096) { src = x; dst = xb; base = (size_t)bid * 1024; }
    else {
        const int r = bid - 4096; const int w = r >> 10; const int off = r & 1023;
        src = (w==0) ? wq : (w==1) ? wk : (w==2) ? wv : wo;
        dst = (w==0) ? qwb : (w==1) ? kwb : (w==2) ? vwb : owb;
        base = (size_t)off * 1024;
    }
    const size_t idx = base + (size_t)threadIdx.x * 4;
    float4 v = *(const float4*)&src[idx];
    ushort4 o;
    o.x = f2bf(v.x); o.y = f2bf(v.y); o.z = f2bf(v.z); o.w = f2bf(v.w);
    *(ushort4*)&dst[idx] = o;
}

// ---------------- MFMA bf16 QKV GEMM: 128x128 tiles (measured optimum) ------
// BK=64, both operands via global_load_lds, XOR-swizzled LDS (k-group cg of
// row r holds global cg ^ (r&7); ds_read unswizzles -> conflict-free b128).
// Staging-bytes floor: Mt=Nt=128 minimizes A*(N/Nt)+B*(M/Mt)=384MB subject to
// grid>=512 and Nt|1024 (r12 falsified smaller tiles: +50% bytes -> +69% time;
// the DMA pipe paces at ~33 GB/s/CU regardless of blocks/CU).
// N=3072 logical over {Wq,Wk,Wv}; q,k -> bf16 head-split [b,h,l,d];
// v -> TRANSPOSED padded [b,h,d,64+l]; k-blocks accumulate kmean_acc.
#define GBK 64

__global__ void mfma_gemm_qkv(
    const unsigned short* __restrict__ A,
    const unsigned short* __restrict__ W0, const unsigned short* __restrict__ W1,
    const unsigned short* __restrict__ W2,
    unsigned short* __restrict__ qo, unsigned short* __restrict__ ko,
    unsigned short* __restrict__ vo, float* __restrict__ kmean_acc)
{
    __shared__ short As[128*GBK];   // [row][kgroup ^ (row&7)] -- swizzled
    __shared__ short Bs[128*GBK];

    const int tid  = threadIdx.x;
    const int wave = tid >> 6, lane = tid & 63;
    const int m0   = blockIdx.x * 128;
    const int n0g  = blockIdx.y * 128;

    const int which = n0g >> 10;                // uniform per block
    const int n0 = n0g & 1023;
    const unsigned short* Wp = (which==0) ? W0 : (which==1) ? W1 : W2;

    const int quad = lane >> 4, lm = lane & 15;
    const int wm = wave >> 1, wn = wave & 1;

    f32x4f acc[4][4] = {};

    // staging geometry: wave stages rows [wave*32, +32), 4 issues x 512 elems
    const int se   = wave * 2048 + lane * 8;
    const int srow = se >> 6;
    const int scg  = (se & 63) >> 3;
    const int sgcol = ((scg ^ (srow & 7)) << 3);

    for (int k0 = 0; k0 < KDIM; k0 += GBK) {
        __syncthreads();
        #pragma unroll
        for (int i = 0; i < 4; ++i) {
            const int ebase = wave * 2048 + i * 512;
            const int row = srow + i * 8;
            __builtin_amdgcn_global_load_lds(
                (const __attribute__((address_space(1))) void*)(A + (size_t)(m0 + row) * KDIM + k0 + sgcol),
                (__attribute__((address_space(3))) void*)(&As[ebase]), 16, 0, 0);
            __builtin_amdgcn_global_load_lds(
                (const __attribute__((address_space(1))) void*)(Wp + (size_t)(n0 + row) * KDIM + k0 + sgcol),
                (__attribute__((address_space(3))) void*)(&Bs[ebase]), 16, 0, 0);
        }
        __syncthreads();

        #pragma unroll
        for (int kk = 0; kk < 2; ++kk) {
            bfrag8 af[4], bf[4];
            #pragma unroll
            for (int t = 0; t < 4; ++t) {
                const int ar = wm*64 + t*16 + lm;
                af[t] = *(const bfrag8*)&As[ar*GBK + (((kk*4 + quad) ^ (ar & 7)) << 3)];
                const int br = wn*64 + t*16 + lm;
                bf[t] = *(const bfrag8*)&Bs[br*GBK + (((kk*4 + quad) ^ (br & 7)) << 3)];
            }
            #pragma unroll
            for (int mt = 0; mt < 4; ++mt)
                #pragma unroll
                for (int nt = 0; nt < 4; ++nt)
                    acc[mt][nt] = __builtin_amdgcn_mfma_f32_16x16x32_bf16(
                        af[mt], bf[nt], acc[mt][nt], 0, 0, 0);
        }
    }

    // epilogue: C/D layout col=lane&15, row=quad*4+reg
    if (which == 2) {
        // v: transposed padded layout, coalesced ushort4 (4 consecutive l)
        #pragma unroll
        for (int mt = 0; mt < 4; ++mt)
            #pragma unroll
            for (int nt = 0; nt < 4; ++nt) {
                const int gn = n0 + wn*64 + nt*16 + lm;
                const int h = gn >> 6, d = gn & 63;
                const int gm0 = m0 + wm*64 + mt*16 + quad*4;
                const int b = gm0 >> 11, l0 = gm0 & (L_SEQ-1);
                ushort4 o;
                o.x = f2bf(acc[mt][nt][0]); o.y = f2bf(acc[mt][nt][1]);
                o.z = f2bf(acc[mt][nt][2]); o.w = f2bf(acc[mt][nt][3]);
                *(ushort4*)&vo[((size_t)((b*HEADS + h)*HD + d))*VSTRIDE + 64 + l0] = o;
            }
    } else {
        unsigned short* Cp = (which==0) ? qo : ko;
        #pragma unroll
        for (int mt = 0; mt < 4; ++mt)
            #pragma unroll
            for (int nt = 0; nt < 4; ++nt) {
                const int gn = n0 + wn*64 + nt*16 + lm;
                const int h = gn >> 6, d = gn & 63;
                #pragma unroll
                for (int r = 0; r < 4; ++r) {
                    const int gm = m0 + wm*64 + mt*16 + quad*4 + r;
                    const int b = gm >> 11, l = gm & (L_SEQ-1);
                    Cp[(((size_t)(b*HEADS + h) * L_SEQ) + l) * HD + d] = f2bf(acc[mt][nt][r]);
                }
            }
        if (which == 1) {
            const int b = m0 >> 11;
            #pragma unroll
            for (int nt = 0; nt < 4; ++nt) {
                const int gn = n0 + wn*64 + nt*16 + lm;
                const int h = gn >> 6, d = gn & 63;
                float s = 0.f;
                #pragma unroll
                for (int mt = 0; mt < 4; ++mt)
                    #pragma unroll
                    for (int r = 0; r < 4; ++r) s += acc[mt][nt][r];
                atomicAdd(&kmean_acc[(size_t)(b*HEADS + h)*HD + d], s);
            }
        }
    }
}

// ---------------- out-projection GEMM: 64x128 tiles (M-split for occupancy) --
// grid (64,8) = 512 blocks = 2/CU: its staging-bytes floor (192MB) with
// uniform residency. Plain coalesced fp32 writes.
__global__ void out_proj_gemm(
    const unsigned short* __restrict__ A, const unsigned short* __restrict__ W,
    float* __restrict__ C)
{
    __shared__ short As[64*GBK];    // 8 KB
    __shared__ short Bs[128*GBK];   // 16 KB

    const int tid  = threadIdx.x;
    const int wave = tid >> 6, lane = tid & 63;
    const int m0   = blockIdx.x * 64;
    const int n0   = blockIdx.y * 128;

    const int quad = lane >> 4, lm = lane & 15;
    const int wm = wave >> 1, wn = wave & 1;   // wave tile: 32 rows x 64 cols

    f32x4f acc[2][4] = {};

    const int sea   = wave * 1024 + lane * 8;
    const int srowa = sea >> 6;
    const int sga   = ((((sea & 63) >> 3) ^ (srowa & 7)) << 3);
    const int seb   = wave * 2048 + lane * 8;
    const int srowb = seb >> 6;
    const int sgb   = ((((seb & 63) >> 3) ^ (srowb & 7)) << 3);

    for (int k0 = 0; k0 < KDIM; k0 += GBK) {
        __syncthreads();
        #pragma unroll
        for (int i = 0; i < 2; ++i) {
            const int ebase = wave * 1024 + i * 512;
            const int row = srowa + i * 8;
            __builtin_amdgcn_global_load_lds(
                (const __attribute__((address_space(1))) void*)(A + (size_t)(m0 + row) * KDIM + k0 + sga),
                (__attribute__((address_space(3))) void*)(&As[ebase]), 16, 0, 0);
        }
        #pragma unroll
        for (int i = 0; i < 4; ++i) {
            const int ebase = wave * 2048 + i * 512;
            const int row = srowb + i * 8;
            __builtin_amdgcn_global_load_lds(
                (const __attribute__((address_space(1))) void*)(W + (size_t)(n0 + row) * KDIM + k0 + sgb),
                (__attribute__((address_space(3))) void*)(&Bs[ebase]), 16, 0, 0);
        }
        __syncthreads();

        #pragma unroll
        for (int kk = 0; kk < 2; ++kk) {
            bfrag8 af[2], bf[4];
            #pragma unroll
            for (int t = 0; t < 2; ++t) {
                const int ar = wm*32 + t*16 + lm;
                af[t] = *(const bfrag8*)&As[ar*GBK + (((kk*4 + quad) ^ (ar & 7)) << 3)];
            }
            #pragma unroll
            for (int t = 0; t < 4; ++t) {
                const int br = wn*64 + t*16 + lm;
                bf[t] = *(const bfrag8*)&Bs[br*GBK + (((kk*4 + quad) ^ (br & 7)) << 3)];
            }
            #pragma unroll
            for (int mt = 0; mt < 2; ++mt)
                #pragma unroll
                for (int nt = 0; nt < 4; ++nt)
                    acc[mt][nt] = __builtin_amdgcn_mfma_f32_16x16x32_bf16(
                        af[mt], bf[nt], acc[mt][nt], 0, 0, 0);
        }
    }

    #pragma unroll
    for (int mt = 0; mt < 2; ++mt)
        #pragma unroll
        for (int nt = 0; nt < 4; ++nt) {
            const int gn = n0 + wn*64 + nt*16 + lm;
            #pragma unroll
            for (int r = 0; r < 4; ++r) {
                const int gm = m0 + wm*32 + mt*16 + quad*4 + r;
                C[(size_t)gm * DMODEL + gn] = acc[mt][nt][r];
            }
        }
}

// ---------------- MFMA windowed attention, zero-staging ----------------
// Block = one (b,h) x 64 queries; 4 waves x 16 queries. Window base j0 = q0-64,
// 6 QK key-tiles (96 rel slots, all computed; invalid -> masked -> P=0).
// K B-frags and V^T B-frags read DIRECTLY from global (16B aligned by design).
// Only LDS: the P round-trip buffer (per-wave rows -> no barriers at all).
#define P_STRIDE 104    // shorts

__global__ __launch_bounds__(256) void attn_kernel(
    const unsigned short* __restrict__ qb, const unsigned short* __restrict__ kb,
    const unsigned short* __restrict__ vt, const float* __restrict__ kmean_acc,
    const float* __restrict__ g_sep, const float* __restrict__ g_align,
    const float* __restrict__ g_coh, unsigned short* __restrict__ out)
{
    __shared__ unsigned short pl[64 * P_STRIDE];

    const int tid = threadIdx.x;
    const int bh = blockIdx.x >> 5;        // 32 q-tiles per (b,h)
    const int qt = blockIdx.x & 31;
    const int q0 = qt * 64;
    const int j0 = q0 - 64;

    const int w = tid >> 6, lane = tid & 63;
    const int quad = lane >> 4, lm = lane & 15;
    const float sep = g_sep[0], align = g_align[0], coh = g_coh[0];

    const unsigned short* kbh = kb + (size_t)bh * L_SEQ * HD;
    const unsigned short* vbh = vt + (size_t)bh * HD * VSTRIDE;

    // Q a-frags (A[m=lm][k=quad*8+j], ksteps 0/1)
    const unsigned short* qrow =
        qb + ((size_t)bh * L_SEQ + q0 + w*16 + lm) * HD + quad * 8;
    bfrag8 qa0 = *(const bfrag8*)qrow;
    bfrag8 qa1 = *(const bfrag8*)(qrow + 32);

    // q . kmean for the cohesion mean (kmean_acc is a SUM over l; scale here)
    const float* kmp = kmean_acc + bh * HD + quad * 8;
    float4 km0 = *(const float4*)(kmp);
    float4 km1 = *(const float4*)(kmp + 4);
    float4 km2 = *(const float4*)(kmp + 32);
    float4 km3 = *(const float4*)(kmp + 36);
    float part =
        bf2f((unsigned short)qa0[0])*km0.x + bf2f((unsigned short)qa0[1])*km0.y +
        bf2f((unsigned short)qa0[2])*km0.z + bf2f((unsigned short)qa0[3])*km0.w +
        bf2f((unsigned short)qa0[4])*km1.x + bf2f((unsigned short)qa0[5])*km1.y +
        bf2f((unsigned short)qa0[6])*km1.z + bf2f((unsigned short)qa0[7])*km1.w +
        bf2f((unsigned short)qa1[0])*km2.x + bf2f((unsigned short)qa1[1])*km2.y +
        bf2f((unsigned short)qa1[2])*km2.z + bf2f((unsigned short)qa1[3])*km2.w +
        bf2f((unsigned short)qa1[4])*km3.x + bf2f((unsigned short)qa1[5])*km3.y +
        bf2f((unsigned short)qa1[6])*km3.z + bf2f((unsigned short)qa1[7])*km3.w;
    part *= (1.f / (float)L_SEQ);
    part += __shfl_xor(part, 16, 64);
    part += __shfl_xor(part, 32, 64);
    // lane g (0..15) holds q.kmean for query w*16+g (replicated across quads)

    // QK^T: 6 tiles x 2 MFMAs, K rows direct from global (clamped; masked later)
    f32x4f sacc[6];
    #pragma unroll
    for (int t = 0; t < 6; ++t) {
        int kr = j0 + w*16 + t*16 + lm;
        kr = kr < 0 ? 0 : (kr >= L_SEQ ? L_SEQ - 1 : kr);
        const unsigned short* kp = kbh + (size_t)kr * HD + quad * 8;
        bfrag8 b0 = *(const bfrag8*)kp;
        bfrag8 b1 = *(const bfrag8*)(kp + 32);
        f32x4f z = {0.f, 0.f, 0.f, 0.f};
        z = __builtin_amdgcn_mfma_f32_16x16x32_bf16(qa0, b0, z, 0, 0, 0);
        sacc[t] = __builtin_amdgcn_mfma_f32_16x16x32_bf16(qa1, b1, z, 0, 0, 0);
    }

    // Reynolds rules + softmax per row (row = quad*4+r), P -> LDS (per-wave rows)
    float rinv[4];
    #pragma unroll
    for (int r = 0; r < 4; ++r) {
        const int row = quad*4 + r;
        const int i   = q0 + w*16 + row;
        const float mean_i = __shfl(part, row, 64) * 0.125f;
        float sc[6]; float mx = -3.0e38f;
        #pragma unroll
        for (int t = 0; t < 6; ++t) {
            const int jabs = j0 + w*16 + t*16 + lm;
            const int dist = i - jabs;
            float s = sacc[t][r] * 0.125f;
            const float sig = 1.f / (1.f + __expf(-s));
            float adj = s * (1.f + align) - sep * sig * sig - coh * fabsf(s - mean_i);
            const bool ok = (dist >= 0) && (dist < 64) && (jabs >= 0);
            sc[t] = ok ? adj : -3.0e38f;
            mx = fmaxf(mx, sc[t]);
        }
        mx = fmaxf(mx, __shfl_xor(mx, 1, 64));
        mx = fmaxf(mx, __shfl_xor(mx, 2, 64));
        mx = fmaxf(mx, __shfl_xor(mx, 4, 64));
        mx = fmaxf(mx, __shfl_xor(mx, 8, 64));
        float ls = 0.f;
        #pragma unroll
        for (int t = 0; t < 6; ++t) {
            const float p = __expf(sc[t] - mx);   // masked -> 0
            ls += p;
            pl[(w*16 + row) * P_STRIDE + t*16 + lm] = f2bf(p);
        }
        ls += __shfl_xor(ls, 1, 64);
        ls += __shfl_xor(ls, 2, 64);
        ls += __shfl_xor(ls, 4, 64);
        ls += __shfl_xor(ls, 8, 64);
        rinv[r] = 1.f / ls;
    }

    // PV: 3 ksteps x 4 d-tiles; V^T B-frags direct from global (padded rows).
    f32x4f oacc[4] = {};
    #pragma unroll
    for (int kk = 0; kk < 3; ++kk) {
        bfrag8 pa = *(const bfrag8*)&pl[(w*16 + lm) * P_STRIDE + kk*32 + quad*8];
        const int loff = 64 + j0 + w*16 + kk*32 + quad*8;
        #pragma unroll
        for (int nt = 0; nt < 4; ++nt) {
            bfrag8 bv = *(const bfrag8*)&vbh[(size_t)(nt*16 + lm) * VSTRIDE + loff];
            oacc[nt] = __builtin_amdgcn_mfma_f32_16x16x32_bf16(pa, bv, oacc[nt], 0, 0, 0);
        }
    }

    const int b = bh >> 4, h = bh & (HEADS - 1);
    #pragma unroll
    for (int nt = 0; nt < 4; ++nt)
        #pragma unroll
        for (int r = 0; r < 4; ++r) {
            const int i = q0 + w*16 + quad*4 + r;
            const int d = nt*16 + lm;
            out[((size_t)(b * L_SEQ + i)) * DMODEL + h * HD + d] =
                f2bf(oacc[nt][r] * rinv[r]);
        }
}

extern "C" void kernel_launch(void* const* d_in, const int* in_sizes, int n_in,
                              void* d_out, int out_size, void* d_ws, size_t ws_size,
                              hipStream_t stream)
{
    (void)in_sizes; (void)n_in; (void)out_size; (void)ws_size;
    const float* x     = (const float*)d_in[0];
    const float* Wq    = (const float*)d_in[1];
    const float* Wk    = (const float*)d_in[2];
    const float* Wv    = (const float*)d_in[3];
    const float* Wo    = (const float*)d_in[4];
    const float* g_sep   = (const float*)d_in[5];
    const float* g_align = (const float*)d_in[6];
    const float* g_coh   = (const float*)d_in[7];
    float* out = (float*)d_out;

    // workspace layout (~49 MB)
    float* kmean_ws = (float*)d_ws;                   // 2048 floats (sum, not mean)
    unsigned short* xb  = (unsigned short*)(kmean_ws + 2048);
    const size_t per = (size_t)MROWS * DMODEL;        // 4 Mi
    unsigned short* wqb = xb  + per;
    unsigned short* wkb = wqb + (size_t)DMODEL*KDIM;
    unsigned short* wvb = wkb + (size_t)DMODEL*KDIM;
    unsigned short* wob = wvb + (size_t)DMODEL*KDIM;
    unsigned short* qb  = wob + (size_t)DMODEL*KDIM;
    unsigned short* kb  = qb  + per;
    unsigned short* vtb = kb  + per;                  // [b,h,d,*] padded: 2048*VSTRIDE
    unsigned short* attb = vtb + (size_t)BATCH*HEADS*HD*VSTRIDE;

    convert_bf16<<<dim3(8193), dim3(256), 0, stream>>>(
        x, Wq, Wk, Wv, Wo, xb, wqb, wkb, wvb, wob, kmean_ws);
    mfma_gemm_qkv<<<dim3(MROWS/128, 3*DMODEL/128), dim3(256), 0, stream>>>(
        xb, wqb, wkb, wvb, qb, kb, vtb, kmean_ws);
    attn_kernel<<<dim3(BATCH*HEADS*(L_SEQ/64)), dim3(256), 0, stream>>>(
        qb, kb, vtb, kmean_ws, g_sep, g_align, g_coh, attb);
    out_proj_gemm<<<dim3(MROWS/64, DMODEL/128), dim3(256), 0, stream>>>(
        attb, wob, out);
}